// Round 16
// baseline (159.955 us; speedup 1.0000x reference)
//
#include <hip/hip_runtime.h>
#include <hip/hip_bf16.h>

typedef short short8 __attribute__((ext_vector_type(8)));
typedef float f32x4 __attribute__((ext_vector_type(4)));

#define MFMA16(a,b,c) __builtin_amdgcn_mfma_f32_16x16x32_bf16((a),(b),(c),0,0,0)

#define NROWS 16384
#define LOG2E 1.44269504088896340736f

// d_ws byte offsets
#define OFF_Q  0u
#define OFF_K  (2u<<20)
#define OFF_V  (4u<<20)
#define OFF_W  (6u<<20)
#define OFF_O  ((6u<<20) + (1u<<18))

__device__ __forceinline__ unsigned short f2bf(float f){
    union { float f; unsigned u; } v; v.f = f;
    unsigned r = v.u + 0x7FFFu + ((v.u >> 16) & 1u);
    return (unsigned short)(r >> 16);
}
__device__ __forceinline__ unsigned pk2(float a, float b){
    union { __hip_bfloat162 h; unsigned u; } c;
    c.h = __float22bfloat162_rn(make_float2(a, b));
    return c.u;
}

union Frag {
    short8 s;
    unsigned short u[8];
    uint2 d2[2];
    uint4 q4;
};

// ---------------------------------------------------------------------------
// W pre-fragmenter: wfrag[w(3)][nt(4)][kk(16)][lane(64)][8] bf16.
// Wq scaled by 0.125*log2e. Block 0 also zeroes the per-gw merge counters
// (runs before attn on the same stream -> deterministic every call).
// ---------------------------------------------------------------------------
__global__ __launch_bounds__(256) void wprep_kernel(
    const float* __restrict__ Wq, const float* __restrict__ Wk,
    const float* __restrict__ Wv, unsigned short* __restrict__ wfrag,
    int* __restrict__ cnt)
{
    if (blockIdx.x == 0 && threadIdx.x < 256) cnt[threadIdx.x] = 0;
    int idx = blockIdx.x * 256 + threadIdx.x;   // 0..12287
    int lane = idx & 63;
    int rest = idx >> 6;        // 0..191
    int kk = rest & 15;
    int nt = (rest >> 4) & 3;
    int w  = rest >> 6;         // 0..2
    const float* W = (w == 0) ? Wq : (w == 1) ? Wk : Wv;
    float scl = (w == 0) ? (0.125f * LOG2E) : 1.0f;
    int n = 16 * nt + (lane & 15);
    int g = lane >> 4;
    Frag o;
#pragma unroll
    for (int e = 0; e < 8; ++e) {
        int k = 32 * kk + 16 * (e >> 2) + 4 * g + (e & 3);
        o.u[e] = f2bf(W[k * 64 + n] * scl);
    }
    *(uint4*)(wfrag + (size_t)idx * 8) = o.q4;
}

// ---------------------------------------------------------------------------
// QKV (r15-proven): 512 blocks x 32 rows, 3 waves (wave w = matrix w, as
// 2 16-row subtiles). x tile staged once to LDS (32x520 bf16, 33 KB); W
// fragments loaded once per kk, reused across both subtiles. W double-
// buffered, sched_barrier-pinned.
// ---------------------------------------------------------------------------
#define LDW(WD, KK) do { \
    _Pragma("unroll") \
    for (int nt_ = 0; nt_ < 4; ++nt_) \
        WD[nt_].q4 = wf[((size_t)(nt_ * 16 + (KK))) * 64 + lane]; \
    } while (0)

#define DOK(WC, KK) do { \
    _Pragma("unroll") \
    for (int M_ = 0; M_ < 2; ++M_) { \
        Frag xf_; \
        const unsigned short* xr_ = &xs[M_ * 16 + l15][32 * (KK) + 4 * g]; \
        xf_.d2[0] = *(const uint2*)xr_; \
        xf_.d2[1] = *(const uint2*)(xr_ + 16); \
        if (w == 2) { \
            _Pragma("unroll") \
            for (int nt_ = 0; nt_ < 4; ++nt_) acc[M_][nt_] = MFMA16(xf_.s, WC[nt_].s, acc[M_][nt_]); \
        } else { \
            _Pragma("unroll") \
            for (int nt_ = 0; nt_ < 4; ++nt_) acc[M_][nt_] = MFMA16(WC[nt_].s, xf_.s, acc[M_][nt_]); \
        } \
    } } while (0)

__global__ __launch_bounds__(192) void qkv_kernel(
    const float* __restrict__ x,
    const float* __restrict__ bq, const float* __restrict__ bk,
    const float* __restrict__ bv,
    const unsigned short* __restrict__ wfrag,
    unsigned short* __restrict__ qfrag,
    unsigned short* __restrict__ kfrag,
    unsigned short* __restrict__ vfrag)
{
    __shared__ unsigned short xs[32][520];      // +8 pad, 33 KB
    const int tid = threadIdx.x;
    const int lane = tid & 63;
    const int w = tid >> 6;                    // 0=Q, 1=K, 2=V
    const int l15 = lane & 15, g = lane >> 4;
    const int rg32 = blockIdx.x;               // 32-row group 0..511
    const float* xbase = x + (size_t)rg32 * 32 * 512;

    for (int i = tid; i < 4096; i += 192) {
        float4 v = *(const float4*)(xbase + i * 4);
        int r_ = i >> 7;
        int c_ = (i & 127) * 4;
        *(uint2*)&xs[r_][c_] = make_uint2(pk2(v.x, v.y), pk2(v.z, v.w));
    }
    __syncthreads();

    f32x4 acc[2][4];
#pragma unroll
    for (int M = 0; M < 2; ++M)
#pragma unroll
        for (int nt = 0; nt < 4; ++nt) acc[M][nt] = (f32x4){0.f,0.f,0.f,0.f};

    const uint4* wf = (const uint4*)wfrag + (size_t)w * 4096;

    Frag wA[4], wB[4];
    LDW(wA, 0);
#pragma unroll
    for (int kp = 0; kp < 8; ++kp) {
        LDW(wB, 2 * kp + 1);
        __builtin_amdgcn_sched_barrier(0);
        DOK(wA, 2 * kp);
        if (2 * kp + 2 < 16) LDW(wA, 2 * kp + 2);
        __builtin_amdgcn_sched_barrier(0);
        DOK(wB, 2 * kp + 1);
    }

#pragma unroll
    for (int M = 0; M < 2; ++M) {
        const int rg  = rg32 * 2 + M;          // 16-row group 0..1023
        const int b   = rg >> 8;
        const int rgb = rg & 255;
        const int tc  = rgb >> 2;
        const int c   = rgb & 3;

        if (w == 0) {
#pragma unroll
            for (int nt = 0; nt < 4; ++nt) {
                float4 bb = *(const float4*)(bq + 16 * nt + 4 * g);
                const float bs = 0.125f * LOG2E;
                float q0 = acc[M][nt][0] + bb.x * bs;
                float q1 = acc[M][nt][1] + bb.y * bs;
                float q2 = acc[M][nt][2] + bb.z * bs;
                float q3 = acc[M][nt][3] + bb.w * bs;
                int ks = nt >> 1, h = nt & 1;
                size_t qoff = ((size_t)(rg * 2 + ks) * 64 + lane) * 8 + h * 4;
                *(uint2*)(qfrag + qoff) = make_uint2(pk2(q0, q1), pk2(q2, q3));
            }
        } else if (w == 1) {
#pragma unroll
            for (int nt = 0; nt < 4; ++nt) {
                float4 bb = *(const float4*)(bk + 16 * nt + 4 * g);
                float k0 = acc[M][nt][0] + bb.x;
                float k1 = acc[M][nt][1] + bb.y;
                float k2 = acc[M][nt][2] + bb.z;
                float k3 = acc[M][nt][3] + bb.w;
                int ks = nt >> 1, h = nt & 1;
                size_t kfi = ((size_t)((b * 64 + tc) * 4 + c) * 2 + ks);
                size_t koff = (kfi * 64 + lane) * 8 + h * 4;
                *(uint2*)(kfrag + koff) = make_uint2(pk2(k0, k1), pk2(k2, k3));
            }
        } else {
            const int vks = c >> 1, vh = c & 1;
#pragma unroll
            for (int nt = 0; nt < 4; ++nt) {
                float bvv = bv[16 * nt + l15];
                float v0 = acc[M][nt][0] + bvv;
                float v1 = acc[M][nt][1] + bvv;
                float v2 = acc[M][nt][2] + bvv;
                float v3 = acc[M][nt][3] + bvv;
                size_t vfi = ((size_t)((b * 64 + tc) * 4 + nt) * 2 + vks);
                size_t voff = (vfi * 64 + lane) * 8 + vh * 4;
                *(uint2*)(vfrag + voff) = make_uint2(pk2(v0, v1), pk2(v2, v3));
            }
        }
    }
}

// ---------------------------------------------------------------------------
// Flash attention + fused merge: 4 waves x 64 q-rows (M=4), KV-split S,
// grid 64*S. Main loop r10/r15-proven. After writing partials, each block
// does release-fence + atomicAdd(cnt[gw]); the LAST block for a gw
// acquire-fences and merges all S partials inline (fixed split order ->
// bit-deterministic), writing the normalized output directly.
// ---------------------------------------------------------------------------
#define LOADK(KD, CH) do { \
    const uint4* p_ = kb0 + (size_t)(CH) * 512; \
    _Pragma("unroll") \
    for (int c_ = 0; c_ < 4; ++c_) { \
        KD[c_][0].q4 = p_[(c_ * 2 + 0) * 64]; \
        KD[c_][1].q4 = p_[(c_ * 2 + 1) * 64]; \
    } } while (0)

#define LOADV(VD, CH) do { \
    const uint4* p_ = vb0 + (size_t)(CH) * 512; \
    _Pragma("unroll") \
    for (int c_ = 0; c_ < 4; ++c_) { \
        VD[c_][0].q4 = p_[(c_ * 2 + 0) * 64]; \
        VD[c_][1].q4 = p_[(c_ * 2 + 1) * 64]; \
    } } while (0)

#define BODY(KC, KN, CH, CHN) do { \
    Frag vC[4][2]; \
    LOADV(vC, CH); \
    LOADK(KN, CHN); \
    __builtin_amdgcn_sched_barrier(0); \
    _Pragma("unroll") \
    for (int M_ = 0; M_ < 4; ++M_) { \
        f32x4 sD[4]; \
        __builtin_amdgcn_s_setprio(1); \
        _Pragma("unroll") \
        for (int c_ = 0; c_ < 4; ++c_) { \
            f32x4 D = (f32x4){0.f,0.f,0.f,0.f}; \
            D = MFMA16(KC[c_][0].s, qf[M_][0].s, D); \
            D = MFMA16(KC[c_][1].s, qf[M_][1].s, D); \
            sD[c_] = D; \
        } \
        __builtin_amdgcn_s_setprio(0); \
        Frag pa0, pa1; \
        _Pragma("unroll") \
        for (int c_ = 0; c_ < 4; ++c_) { \
            float p0 = __builtin_exp2f(sD[c_][0]); \
            float p1 = __builtin_exp2f(sD[c_][1]); \
            float p2 = __builtin_exp2f(sD[c_][2]); \
            float p3 = __builtin_exp2f(sD[c_][3]); \
            uint2 pk_ = make_uint2(pk2(p0, p1), pk2(p2, p3)); \
            if (c_ < 2) pa0.d2[c_ & 1] = pk_; else pa1.d2[c_ & 1] = pk_; \
        } \
        __builtin_amdgcn_s_setprio(1); \
        lacc[M_] = MFMA16(pa0.s, ones_.s, lacc[M_]); \
        lacc[M_] = MFMA16(pa1.s, ones_.s, lacc[M_]); \
        _Pragma("unroll") \
        for (int dc_ = 0; dc_ < 4; ++dc_) { \
            acc[M_][dc_] = MFMA16(pa0.s, vC[dc_][0].s, acc[M_][dc_]); \
            acc[M_][dc_] = MFMA16(pa1.s, vC[dc_][1].s, acc[M_][dc_]); \
        } \
        __builtin_amdgcn_s_setprio(0); \
    } } while (0)

__global__ __launch_bounds__(256, 2) void attn_kernel(
    const unsigned short* __restrict__ qfrag,
    const unsigned short* __restrict__ kfrag,
    const unsigned short* __restrict__ vfrag,
    uint2* __restrict__ OpartU, float* __restrict__ lml,
    int* __restrict__ cnt, float* __restrict__ out,
    int CPS, int SBITS)
{
    __shared__ int lastflag;
    const int tid = threadIdx.x;
    const int lane = tid & 63;
    const int w = tid >> 6;
    const int l15 = lane & 15, g = lane >> 4;
    const int split  = blockIdx.x & ((1 << SBITS) - 1);   // XCD-pinned
    const int qblock = blockIdx.x >> SBITS;
    const int gw = qblock * 4 + w;             // 64-row group 0..255
    const int b = gw >> 6;                     // batch
    const int tcg0 = b * 64 + split * CPS;

    const uint4* qf4 = (const uint4*)qfrag;
    const uint4* kb0 = (const uint4*)kfrag + (size_t)tcg0 * 512 + lane;
    const uint4* vb0 = (const uint4*)vfrag + (size_t)tcg0 * 512 + lane;

    Frag qf[4][2];
#pragma unroll
    for (int M = 0; M < 4; ++M)
#pragma unroll
        for (int ks = 0; ks < 2; ++ks)
            qf[M][ks].q4 = qf4[((size_t)((gw * 4 + M) * 2 + ks)) * 64 + lane];

    Frag ones_;
    ones_.d2[0] = make_uint2(0x3F803F80u, 0x3F803F80u);
    ones_.d2[1] = make_uint2(0x3F803F80u, 0x3F803F80u);

    f32x4 acc[4][4], lacc[4];
#pragma unroll
    for (int M = 0; M < 4; ++M) {
        lacc[M] = (f32x4){0.f,0.f,0.f,0.f};
#pragma unroll
        for (int dc = 0; dc < 4; ++dc) acc[M][dc] = (f32x4){0.f,0.f,0.f,0.f};
    }

    Frag kA[4][2], kB[4][2];
    LOADK(kA, 0);

#pragma unroll 1
    for (int ch = 0; ch < CPS; ch += 2) {
        int c1 = (ch + 1 < CPS) ? (ch + 1) : ch;
        int c2 = (ch + 2 < CPS) ? (ch + 2) : ch;
        BODY(kA, kB, ch, c1);
        BODY(kB, kA, c1, c2);
    }

    // partials: bf16 O, fp32 l (lacc[M][r] = l for q-row 16M+4g+r)
    // NOTE: gw wave index here differs per wave; all 4 waves of the block
    // write distinct gw -> the counter is per-gw, incremented by each of
    // the S blocks that computed a split of that gw... but each block's
    // wave w handles gw = qblock*4+w, and all S split-blocks with the same
    // qblock cover the same 4 gw values. Count at block granularity on
    // gw0 = qblock*4 (one atomic per block), merge all 4 gw of the qblock.
#pragma unroll
    for (int M = 0; M < 4; ++M) {
#pragma unroll
        for (int dc = 0; dc < 4; ++dc)
            OpartU[((size_t)(split * 256 + gw) * 16 + M * 4 + dc) * 64 + lane] =
                make_uint2(pk2(acc[M][dc][0], acc[M][dc][1]),
                           pk2(acc[M][dc][2], acc[M][dc][3]));
        if (l15 == 0)
            *(f32x4*)(lml + (size_t)(split * 256 + gw) * 64 + M * 16 + 4 * g) = lacc[M];
    }

    // ---- fused merge: last split-block for this qblock merges ----
    __threadfence();
    if (tid == 0) {
        int old = atomicAdd(&cnt[qblock], 1);
        lastflag = (old == (1 << SBITS) - 1);
    }
    __syncthreads();
    if (!lastflag) return;
    __threadfence();

    const int S = 1 << SBITS;
    const int dc = (tid >> 6) & 3;   // reuse 256 threads: 64 lanes x 4 dc
#pragma unroll 1
    for (int mw = 0; mw < 4; ++mw) {        // the 4 gw of this qblock
        const int mgw = qblock * 4 + mw;
#pragma unroll
        for (int M = 0; M < 4; ++M) {
            float o0 = 0.f, o1 = 0.f, o2 = 0.f, o3 = 0.f;
            float L0 = 0.f, L1 = 0.f, L2 = 0.f, L3 = 0.f;
            for (int s = 0; s < S; ++s) {
                uint2 pv = OpartU[((size_t)(s * 256 + mgw) * 16 + M * 4 + dc) * 64 + lane];
                float4 lv = *(const float4*)(lml + (size_t)(s * 256 + mgw) * 64 + M * 16 + 4 * g);
                o0 += __uint_as_float(pv.x << 16);
                o1 += __uint_as_float(pv.x & 0xFFFF0000u);
                o2 += __uint_as_float(pv.y << 16);
                o3 += __uint_as_float(pv.y & 0xFFFF0000u);
                L0 += lv.x; L1 += lv.y; L2 += lv.z; L3 += lv.w;
            }
            size_t row = (size_t)mgw * 64 + M * 16 + 4 * g;
            int col = 16 * dc + l15;
            out[(row + 0) * 64 + col] = o0 / L0;
            out[(row + 1) * 64 + col] = o1 / L1;
            out[(row + 2) * 64 + col] = o2 / L2;
            out[(row + 3) * 64 + col] = o3 / L3;
        }
    }
}

extern "C" void kernel_launch(void* const* d_in, const int* in_sizes, int n_in,
                              void* d_out, int out_size, void* d_ws, size_t ws_size,
                              hipStream_t stream) {
    (void)in_sizes; (void)n_in; (void)out_size;
    const float* x  = (const float*)d_in[0];
    const float* Wq = (const float*)d_in[1];
    const float* bq = (const float*)d_in[2];
    const float* Wk = (const float*)d_in[3];
    const float* bk = (const float*)d_in[4];
    const float* Wv = (const float*)d_in[5];
    const float* bv = (const float*)d_in[6];
    float* out = (float*)d_out;

    char* ws = (char*)d_ws;
    unsigned short* qfrag = (unsigned short*)(ws + OFF_Q);
    unsigned short* kfrag = (unsigned short*)(ws + OFF_K);
    unsigned short* vfrag = (unsigned short*)(ws + OFF_V);
    unsigned short* wfrag = (unsigned short*)(ws + OFF_W);

    const size_t oneO = (size_t)256 * 16 * 64 * 8;  // 2 MB per split (bf16)
    const size_t oneL = (size_t)256 * 64 * 4;       // 64 KB per split
    int S = 8, SBITS = 3;
    if (ws_size < (size_t)OFF_O + 8 * (oneO + oneL) + 1024) { S = 4; SBITS = 2; }
    if (ws_size < (size_t)OFF_O + 4 * (oneO + oneL) + 1024) { S = 2; SBITS = 1; }
    uint2* OpartU = (uint2*)(ws + OFF_O);
    float* lml    = (float*)(ws + OFF_O + (size_t)S * oneO);
    int*   cnt    = (int*)(ws + OFF_O + (size_t)S * (oneO + oneL));
    int CPS = 64 / S;

    hipLaunchKernelGGL(wprep_kernel, dim3(48), dim3(256), 0, stream,
                       Wq, Wk, Wv, wfrag, cnt);
    hipLaunchKernelGGL(qkv_kernel, dim3(512), dim3(192), 0, stream,
                       x, bq, bk, bv, wfrag, qfrag, kfrag, vfrag);
    hipLaunchKernelGGL(attn_kernel, dim3(64 * S), dim3(256), 0, stream,
                       qfrag, kfrag, vfrag, OpartU, lml, cnt, out, CPS, SBITS);
}

// Round 17
// 58.406 us; speedup vs baseline: 2.7387x; 2.7387x over previous
//
#include <hip/hip_runtime.h>
#include <hip/hip_bf16.h>

typedef short short8 __attribute__((ext_vector_type(8)));
typedef float f32x4 __attribute__((ext_vector_type(4)));

#define MFMA16(a,b,c) __builtin_amdgcn_mfma_f32_16x16x32_bf16((a),(b),(c),0,0,0)

#define NROWS 16384
#define LOG2E 1.44269504088896340736f

// d_ws byte offsets
#define OFF_Q  0u
#define OFF_K  (2u<<20)
#define OFF_V  (4u<<20)
#define OFF_W  (6u<<20)
#define OFF_O  ((6u<<20) + (1u<<18))

__device__ __forceinline__ unsigned short f2bf(float f){
    union { float f; unsigned u; } v; v.f = f;
    unsigned r = v.u + 0x7FFFu + ((v.u >> 16) & 1u);
    return (unsigned short)(r >> 16);
}
__device__ __forceinline__ unsigned pk2(float a, float b){
    union { __hip_bfloat162 h; unsigned u; } c;
    c.h = __float22bfloat162_rn(make_float2(a, b));
    return c.u;
}

union Frag {
    short8 s;
    unsigned short u[8];
    uint2 d2[2];
    uint4 q4;
};

// ---------------------------------------------------------------------------
// W pre-fragmenter: wfrag[w(3)][nt(4)][kk(16)][lane(64)][8] bf16.
// Wq scaled by 0.125*log2e (scores in log2 domain -> exp2 softmax).
// ---------------------------------------------------------------------------
__global__ __launch_bounds__(256) void wprep_kernel(
    const float* __restrict__ Wq, const float* __restrict__ Wk,
    const float* __restrict__ Wv, unsigned short* __restrict__ wfrag)
{
    int idx = blockIdx.x * 256 + threadIdx.x;   // 0..12287
    int lane = idx & 63;
    int rest = idx >> 6;        // 0..191
    int kk = rest & 15;
    int nt = (rest >> 4) & 3;
    int w  = rest >> 6;         // 0..2
    const float* W = (w == 0) ? Wq : (w == 1) ? Wk : Wv;
    float scl = (w == 0) ? (0.125f * LOG2E) : 1.0f;
    int n = 16 * nt + (lane & 15);
    int g = lane >> 4;
    Frag o;
#pragma unroll
    for (int e = 0; e < 8; ++e) {
        int k = 32 * kk + 16 * (e >> 2) + 4 * g + (e & 3);
        o.u[e] = f2bf(W[k * 64 + n] * scl);
    }
    *(uint4*)(wfrag + (size_t)idx * 8) = o.q4;
}

// ---------------------------------------------------------------------------
// QKV (r15-proven): 512 blocks x 32 rows, 3 waves (wave w = matrix w, as
// 2 16-row subtiles). x tile staged once to LDS (32x520 bf16, 33 KB); W
// fragments loaded once per kk, reused across both subtiles. W double-
// buffered, sched_barrier-pinned.
// ---------------------------------------------------------------------------
#define LDW(WD, KK) do { \
    _Pragma("unroll") \
    for (int nt_ = 0; nt_ < 4; ++nt_) \
        WD[nt_].q4 = wf[((size_t)(nt_ * 16 + (KK))) * 64 + lane]; \
    } while (0)

#define DOK(WC, KK) do { \
    _Pragma("unroll") \
    for (int M_ = 0; M_ < 2; ++M_) { \
        Frag xf_; \
        const unsigned short* xr_ = &xs[M_ * 16 + l15][32 * (KK) + 4 * g]; \
        xf_.d2[0] = *(const uint2*)xr_; \
        xf_.d2[1] = *(const uint2*)(xr_ + 16); \
        if (w == 2) { \
            _Pragma("unroll") \
            for (int nt_ = 0; nt_ < 4; ++nt_) acc[M_][nt_] = MFMA16(xf_.s, WC[nt_].s, acc[M_][nt_]); \
        } else { \
            _Pragma("unroll") \
            for (int nt_ = 0; nt_ < 4; ++nt_) acc[M_][nt_] = MFMA16(WC[nt_].s, xf_.s, acc[M_][nt_]); \
        } \
    } } while (0)

__global__ __launch_bounds__(192) void qkv_kernel(
    const float* __restrict__ x,
    const float* __restrict__ bq, const float* __restrict__ bk,
    const float* __restrict__ bv,
    const unsigned short* __restrict__ wfrag,
    unsigned short* __restrict__ qfrag,
    unsigned short* __restrict__ kfrag,
    unsigned short* __restrict__ vfrag)
{
    __shared__ unsigned short xs[32][520];      // +8 pad, 33 KB
    const int tid = threadIdx.x;
    const int lane = tid & 63;
    const int w = tid >> 6;                    // 0=Q, 1=K, 2=V
    const int l15 = lane & 15, g = lane >> 4;
    const int rg32 = blockIdx.x;               // 32-row group 0..511
    const float* xbase = x + (size_t)rg32 * 32 * 512;

    for (int i = tid; i < 4096; i += 192) {
        float4 v = *(const float4*)(xbase + i * 4);
        int r_ = i >> 7;
        int c_ = (i & 127) * 4;
        *(uint2*)&xs[r_][c_] = make_uint2(pk2(v.x, v.y), pk2(v.z, v.w));
    }
    __syncthreads();

    f32x4 acc[2][4];
#pragma unroll
    for (int M = 0; M < 2; ++M)
#pragma unroll
        for (int nt = 0; nt < 4; ++nt) acc[M][nt] = (f32x4){0.f,0.f,0.f,0.f};

    const uint4* wf = (const uint4*)wfrag + (size_t)w * 4096;

    Frag wA[4], wB[4];
    LDW(wA, 0);
#pragma unroll
    for (int kp = 0; kp < 8; ++kp) {
        LDW(wB, 2 * kp + 1);
        __builtin_amdgcn_sched_barrier(0);
        DOK(wA, 2 * kp);
        if (2 * kp + 2 < 16) LDW(wA, 2 * kp + 2);
        __builtin_amdgcn_sched_barrier(0);
        DOK(wB, 2 * kp + 1);
    }

#pragma unroll
    for (int M = 0; M < 2; ++M) {
        const int rg  = rg32 * 2 + M;          // 16-row group 0..1023
        const int b   = rg >> 8;
        const int rgb = rg & 255;
        const int tc  = rgb >> 2;
        const int c   = rgb & 3;

        if (w == 0) {
#pragma unroll
            for (int nt = 0; nt < 4; ++nt) {
                float4 bb = *(const float4*)(bq + 16 * nt + 4 * g);
                const float bs = 0.125f * LOG2E;
                float q0 = acc[M][nt][0] + bb.x * bs;
                float q1 = acc[M][nt][1] + bb.y * bs;
                float q2 = acc[M][nt][2] + bb.z * bs;
                float q3 = acc[M][nt][3] + bb.w * bs;
                int ks = nt >> 1, h = nt & 1;
                size_t qoff = ((size_t)(rg * 2 + ks) * 64 + lane) * 8 + h * 4;
                *(uint2*)(qfrag + qoff) = make_uint2(pk2(q0, q1), pk2(q2, q3));
            }
        } else if (w == 1) {
#pragma unroll
            for (int nt = 0; nt < 4; ++nt) {
                float4 bb = *(const float4*)(bk + 16 * nt + 4 * g);
                float k0 = acc[M][nt][0] + bb.x;
                float k1 = acc[M][nt][1] + bb.y;
                float k2 = acc[M][nt][2] + bb.z;
                float k3 = acc[M][nt][3] + bb.w;
                int ks = nt >> 1, h = nt & 1;
                size_t kfi = ((size_t)((b * 64 + tc) * 4 + c) * 2 + ks);
                size_t koff = (kfi * 64 + lane) * 8 + h * 4;
                *(uint2*)(kfrag + koff) = make_uint2(pk2(k0, k1), pk2(k2, k3));
            }
        } else {
            const int vks = c >> 1, vh = c & 1;
#pragma unroll
            for (int nt = 0; nt < 4; ++nt) {
                float bvv = bv[16 * nt + l15];
                float v0 = acc[M][nt][0] + bvv;
                float v1 = acc[M][nt][1] + bvv;
                float v2 = acc[M][nt][2] + bvv;
                float v3 = acc[M][nt][3] + bvv;
                size_t vfi = ((size_t)((b * 64 + tc) * 4 + nt) * 2 + vks);
                size_t voff = (vfi * 64 + lane) * 8 + vh * 4;
                *(uint2*)(vfrag + voff) = make_uint2(pk2(v0, v1), pk2(v2, v3));
            }
        }
    }
}

// ---------------------------------------------------------------------------
// Flash attention (r15 structure, CPS templated): 4 waves x 64 q-rows
// (M=4), KV-split S, grid 64*S. FULLY UNROLLED chunk loop (compile-time
// CPS) -> straight-line code, so the scheduler can hoist body N+1's loads
// into body N's compute (runtime loop's backedge previously forbade it).
// K reg-double-buffered, V at body top, sched_barrier-pinned. setprio
// around MFMA. Static-max log2 softmax. l via MFMA-with-ones.
// ---------------------------------------------------------------------------
#define LOADK(KD, CH) do { \
    const uint4* p_ = kb0 + (size_t)(CH) * 512; \
    _Pragma("unroll") \
    for (int c_ = 0; c_ < 4; ++c_) { \
        KD[c_][0].q4 = p_[(c_ * 2 + 0) * 64]; \
        KD[c_][1].q4 = p_[(c_ * 2 + 1) * 64]; \
    } } while (0)

#define LOADV(VD, CH) do { \
    const uint4* p_ = vb0 + (size_t)(CH) * 512; \
    _Pragma("unroll") \
    for (int c_ = 0; c_ < 4; ++c_) { \
        VD[c_][0].q4 = p_[(c_ * 2 + 0) * 64]; \
        VD[c_][1].q4 = p_[(c_ * 2 + 1) * 64]; \
    } } while (0)

#define BODY(KC, KN, CH, CHN) do { \
    Frag vC[4][2]; \
    LOADV(vC, CH); \
    LOADK(KN, CHN); \
    __builtin_amdgcn_sched_barrier(0); \
    _Pragma("unroll") \
    for (int M_ = 0; M_ < 4; ++M_) { \
        f32x4 sD[4]; \
        __builtin_amdgcn_s_setprio(1); \
        _Pragma("unroll") \
        for (int c_ = 0; c_ < 4; ++c_) { \
            f32x4 D = (f32x4){0.f,0.f,0.f,0.f}; \
            D = MFMA16(KC[c_][0].s, qf[M_][0].s, D); \
            D = MFMA16(KC[c_][1].s, qf[M_][1].s, D); \
            sD[c_] = D; \
        } \
        __builtin_amdgcn_s_setprio(0); \
        Frag pa0, pa1; \
        _Pragma("unroll") \
        for (int c_ = 0; c_ < 4; ++c_) { \
            float p0 = __builtin_exp2f(sD[c_][0]); \
            float p1 = __builtin_exp2f(sD[c_][1]); \
            float p2 = __builtin_exp2f(sD[c_][2]); \
            float p3 = __builtin_exp2f(sD[c_][3]); \
            uint2 pk_ = make_uint2(pk2(p0, p1), pk2(p2, p3)); \
            if (c_ < 2) pa0.d2[c_ & 1] = pk_; else pa1.d2[c_ & 1] = pk_; \
        } \
        __builtin_amdgcn_s_setprio(1); \
        lacc[M_] = MFMA16(pa0.s, ones_.s, lacc[M_]); \
        lacc[M_] = MFMA16(pa1.s, ones_.s, lacc[M_]); \
        _Pragma("unroll") \
        for (int dc_ = 0; dc_ < 4; ++dc_) { \
            acc[M_][dc_] = MFMA16(pa0.s, vC[dc_][0].s, acc[M_][dc_]); \
            acc[M_][dc_] = MFMA16(pa1.s, vC[dc_][1].s, acc[M_][dc_]); \
        } \
        __builtin_amdgcn_s_setprio(0); \
    } } while (0)

template<int CPST>
__global__ __launch_bounds__(256, 2) void attn_kernel(
    const unsigned short* __restrict__ qfrag,
    const unsigned short* __restrict__ kfrag,
    const unsigned short* __restrict__ vfrag,
    uint2* __restrict__ OpartU, float* __restrict__ lml,
    int SBITS)
{
    const int tid = threadIdx.x;
    const int lane = tid & 63;
    const int w = tid >> 6;
    const int l15 = lane & 15, g = lane >> 4;
    const int split  = blockIdx.x & ((1 << SBITS) - 1);   // XCD-pinned
    const int qblock = blockIdx.x >> SBITS;
    const int gw = qblock * 4 + w;             // 64-row group 0..255
    const int b = gw >> 6;                     // batch
    const int tcg0 = b * 64 + split * CPST;

    const uint4* qf4 = (const uint4*)qfrag;
    const uint4* kb0 = (const uint4*)kfrag + (size_t)tcg0 * 512 + lane;
    const uint4* vb0 = (const uint4*)vfrag + (size_t)tcg0 * 512 + lane;

    Frag qf[4][2];
#pragma unroll
    for (int M = 0; M < 4; ++M)
#pragma unroll
        for (int ks = 0; ks < 2; ++ks)
            qf[M][ks].q4 = qf4[((size_t)((gw * 4 + M) * 2 + ks)) * 64 + lane];

    Frag ones_;
    ones_.d2[0] = make_uint2(0x3F803F80u, 0x3F803F80u);
    ones_.d2[1] = make_uint2(0x3F803F80u, 0x3F803F80u);

    f32x4 acc[4][4], lacc[4];
#pragma unroll
    for (int M = 0; M < 4; ++M) {
        lacc[M] = (f32x4){0.f,0.f,0.f,0.f};
#pragma unroll
        for (int dc = 0; dc < 4; ++dc) acc[M][dc] = (f32x4){0.f,0.f,0.f,0.f};
    }

    Frag kA[4][2], kB[4][2];
    LOADK(kA, 0);

#pragma unroll
    for (int ch = 0; ch < CPST; ch += 2) {
        const int c1 = (ch + 1 < CPST) ? (ch + 1) : ch;
        const int c2 = (ch + 2 < CPST) ? (ch + 2) : ch;
        BODY(kA, kB, ch, c1);
        BODY(kB, kA, c1, c2);
    }

    // epilogue: bf16 partials; lacc[M][r] = l for q-row 16M+4g+r
#pragma unroll
    for (int M = 0; M < 4; ++M) {
#pragma unroll
        for (int dc = 0; dc < 4; ++dc)
            OpartU[((size_t)(split * 256 + gw) * 16 + M * 4 + dc) * 64 + lane] =
                make_uint2(pk2(acc[M][dc][0], acc[M][dc][1]),
                           pk2(acc[M][dc][2], acc[M][dc][3]));
        if (l15 == 0)
            *(f32x4*)(lml + (size_t)(split * 256 + gw) * 64 + M * 16 + 4 * g) = lacc[M];
    }
}

// ---------------------------------------------------------------------------
// Merge S partials (shared static max -> plain weighted sums, no exp).
// ---------------------------------------------------------------------------
__global__ __launch_bounds__(256) void merge_kernel(
    const uint2* __restrict__ OpartU, const float* __restrict__ lml,
    float* __restrict__ out, int S)
{
    int gid = blockIdx.x * 256 + threadIdx.x;   // 0..262143
    int lane = gid & 63;
    int dc = (gid >> 6) & 3;
    int M  = (gid >> 8) & 3;
    int gw = gid >> 10;                         // 0..255
    int l15 = lane & 15, g = lane >> 4;

    float o0 = 0.f, o1 = 0.f, o2 = 0.f, o3 = 0.f;
    float L0 = 0.f, L1 = 0.f, L2 = 0.f, L3 = 0.f;
    for (int s = 0; s < S; ++s) {
        uint2 pv = OpartU[((size_t)(s * 256 + gw) * 16 + M * 4 + dc) * 64 + lane];
        float4 lv = *(const float4*)(lml + (size_t)(s * 256 + gw) * 64 + M * 16 + 4 * g);
        o0 += __uint_as_float(pv.x << 16);
        o1 += __uint_as_float(pv.x & 0xFFFF0000u);
        o2 += __uint_as_float(pv.y << 16);
        o3 += __uint_as_float(pv.y & 0xFFFF0000u);
        L0 += lv.x; L1 += lv.y; L2 += lv.z; L3 += lv.w;
    }
    size_t row = (size_t)gw * 64 + M * 16 + 4 * g;
    int col = 16 * dc + l15;
    out[(row + 0) * 64 + col] = o0 / L0;
    out[(row + 1) * 64 + col] = o1 / L1;
    out[(row + 2) * 64 + col] = o2 / L2;
    out[(row + 3) * 64 + col] = o3 / L3;
}

extern "C" void kernel_launch(void* const* d_in, const int* in_sizes, int n_in,
                              void* d_out, int out_size, void* d_ws, size_t ws_size,
                              hipStream_t stream) {
    (void)in_sizes; (void)n_in; (void)out_size;
    const float* x  = (const float*)d_in[0];
    const float* Wq = (const float*)d_in[1];
    const float* bq = (const float*)d_in[2];
    const float* Wk = (const float*)d_in[3];
    const float* bk = (const float*)d_in[4];
    const float* Wv = (const float*)d_in[5];
    const float* bv = (const float*)d_in[6];
    float* out = (float*)d_out;

    char* ws = (char*)d_ws;
    unsigned short* qfrag = (unsigned short*)(ws + OFF_Q);
    unsigned short* kfrag = (unsigned short*)(ws + OFF_K);
    unsigned short* vfrag = (unsigned short*)(ws + OFF_V);
    unsigned short* wfrag = (unsigned short*)(ws + OFF_W);

    const size_t oneO = (size_t)256 * 16 * 64 * 8;  // 2 MB per split (bf16)
    const size_t oneL = (size_t)256 * 64 * 4;       // 64 KB per split
    int S = 8, SBITS = 3;
    if (ws_size < (size_t)OFF_O + 8 * (oneO + oneL)) { S = 4; SBITS = 2; }
    if (ws_size < (size_t)OFF_O + 4 * (oneO + oneL)) { S = 2; SBITS = 1; }
    uint2* OpartU = (uint2*)(ws + OFF_O);
    float* lml    = (float*)(ws + OFF_O + (size_t)S * oneO);

    hipLaunchKernelGGL(wprep_kernel, dim3(48), dim3(256), 0, stream,
                       Wq, Wk, Wv, wfrag);
    hipLaunchKernelGGL(qkv_kernel, dim3(512), dim3(192), 0, stream,
                       x, bq, bk, bv, wfrag, qfrag, kfrag, vfrag);
    if (S == 8)
        hipLaunchKernelGGL(attn_kernel<8>,  dim3(64 * 8), dim3(256), 0, stream,
                           qfrag, kfrag, vfrag, OpartU, lml, 3);
    else if (S == 4)
        hipLaunchKernelGGL(attn_kernel<16>, dim3(64 * 4), dim3(256), 0, stream,
                           qfrag, kfrag, vfrag, OpartU, lml, 2);
    else
        hipLaunchKernelGGL(attn_kernel<32>, dim3(64 * 2), dim3(256), 0, stream,
                           qfrag, kfrag, vfrag, OpartU, lml, 1);
    hipLaunchKernelGGL(merge_kernel, dim3(1024), dim3(256), 0, stream,
                       OpartU, lml, out, S);
}

// Round 18
// 57.964 us; speedup vs baseline: 2.7596x; 1.0076x over previous
//
#include <hip/hip_runtime.h>
#include <hip/hip_bf16.h>

typedef short short8 __attribute__((ext_vector_type(8)));
typedef float f32x4 __attribute__((ext_vector_type(4)));

#define MFMA16(a,b,c) __builtin_amdgcn_mfma_f32_16x16x32_bf16((a),(b),(c),0,0,0)

#define NROWS 16384
#define LOG2E 1.44269504088896340736f

// d_ws byte offsets
#define OFF_Q  0u
#define OFF_K  (2u<<20)
#define OFF_V  (4u<<20)
#define OFF_W  (6u<<20)
#define OFF_O  ((6u<<20) + (1u<<18))

__device__ __forceinline__ unsigned short f2bf(float f){
    union { float f; unsigned u; } v; v.f = f;
    unsigned r = v.u + 0x7FFFu + ((v.u >> 16) & 1u);
    return (unsigned short)(r >> 16);
}
__device__ __forceinline__ unsigned pk2(float a, float b){
    union { __hip_bfloat162 h; unsigned u; } c;
    c.h = __float22bfloat162_rn(make_float2(a, b));
    return c.u;
}

union Frag {
    short8 s;
    unsigned short u[8];
    uint2 d2[2];
    uint4 q4;
};

// ---------------------------------------------------------------------------
// W pre-fragmenter: wfrag[w(3)][nt(4)][kk(16)][lane(64)][8] bf16.
// Wq scaled by 0.125*log2e (scores in log2 domain -> exp2 softmax).
// ---------------------------------------------------------------------------
__global__ __launch_bounds__(256) void wprep_kernel(
    const float* __restrict__ Wq, const float* __restrict__ Wk,
    const float* __restrict__ Wv, unsigned short* __restrict__ wfrag)
{
    int idx = blockIdx.x * 256 + threadIdx.x;   // 0..12287
    int lane = idx & 63;
    int rest = idx >> 6;        // 0..191
    int kk = rest & 15;
    int nt = (rest >> 4) & 3;
    int w  = rest >> 6;         // 0..2
    const float* W = (w == 0) ? Wq : (w == 1) ? Wk : Wv;
    float scl = (w == 0) ? (0.125f * LOG2E) : 1.0f;
    int n = 16 * nt + (lane & 15);
    int g = lane >> 4;
    Frag o;
#pragma unroll
    for (int e = 0; e < 8; ++e) {
        int k = 32 * kk + 16 * (e >> 2) + 4 * g + (e & 3);
        o.u[e] = f2bf(W[k * 64 + n] * scl);
    }
    *(uint4*)(wfrag + (size_t)idx * 8) = o.q4;
}

// ---------------------------------------------------------------------------
// QKV (r15-proven): 512 blocks x 32 rows, 3 waves (wave w = matrix w, as
// 2 16-row subtiles). x tile staged once to LDS (32x520 bf16, 33 KB); W
// fragments loaded once per kk, reused across both subtiles. W double-
// buffered, sched_barrier-pinned.
// ---------------------------------------------------------------------------
#define LDW(WD, KK) do { \
    _Pragma("unroll") \
    for (int nt_ = 0; nt_ < 4; ++nt_) \
        WD[nt_].q4 = wf[((size_t)(nt_ * 16 + (KK))) * 64 + lane]; \
    } while (0)

#define DOK(WC, KK) do { \
    _Pragma("unroll") \
    for (int M_ = 0; M_ < 2; ++M_) { \
        Frag xf_; \
        const unsigned short* xr_ = &xs[M_ * 16 + l15][32 * (KK) + 4 * g]; \
        xf_.d2[0] = *(const uint2*)xr_; \
        xf_.d2[1] = *(const uint2*)(xr_ + 16); \
        if (w == 2) { \
            _Pragma("unroll") \
            for (int nt_ = 0; nt_ < 4; ++nt_) acc[M_][nt_] = MFMA16(xf_.s, WC[nt_].s, acc[M_][nt_]); \
        } else { \
            _Pragma("unroll") \
            for (int nt_ = 0; nt_ < 4; ++nt_) acc[M_][nt_] = MFMA16(WC[nt_].s, xf_.s, acc[M_][nt_]); \
        } \
    } } while (0)

__global__ __launch_bounds__(192) void qkv_kernel(
    const float* __restrict__ x,
    const float* __restrict__ bq, const float* __restrict__ bk,
    const float* __restrict__ bv,
    const unsigned short* __restrict__ wfrag,
    unsigned short* __restrict__ qfrag,
    unsigned short* __restrict__ kfrag,
    unsigned short* __restrict__ vfrag)
{
    __shared__ unsigned short xs[32][520];      // +8 pad, 33 KB
    const int tid = threadIdx.x;
    const int lane = tid & 63;
    const int w = tid >> 6;                    // 0=Q, 1=K, 2=V
    const int l15 = lane & 15, g = lane >> 4;
    const int rg32 = blockIdx.x;               // 32-row group 0..511
    const float* xbase = x + (size_t)rg32 * 32 * 512;

    for (int i = tid; i < 4096; i += 192) {
        float4 v = *(const float4*)(xbase + i * 4);
        int r_ = i >> 7;
        int c_ = (i & 127) * 4;
        *(uint2*)&xs[r_][c_] = make_uint2(pk2(v.x, v.y), pk2(v.z, v.w));
    }
    __syncthreads();

    f32x4 acc[2][4];
#pragma unroll
    for (int M = 0; M < 2; ++M)
#pragma unroll
        for (int nt = 0; nt < 4; ++nt) acc[M][nt] = (f32x4){0.f,0.f,0.f,0.f};

    const uint4* wf = (const uint4*)wfrag + (size_t)w * 4096;

    Frag wA[4], wB[4];
    LDW(wA, 0);
#pragma unroll
    for (int kp = 0; kp < 8; ++kp) {
        LDW(wB, 2 * kp + 1);
        __builtin_amdgcn_sched_barrier(0);
        DOK(wA, 2 * kp);
        if (2 * kp + 2 < 16) LDW(wA, 2 * kp + 2);
        __builtin_amdgcn_sched_barrier(0);
        DOK(wB, 2 * kp + 1);
    }

#pragma unroll
    for (int M = 0; M < 2; ++M) {
        const int rg  = rg32 * 2 + M;          // 16-row group 0..1023
        const int b   = rg >> 8;
        const int rgb = rg & 255;
        const int tc  = rgb >> 2;
        const int c   = rgb & 3;

        if (w == 0) {
#pragma unroll
            for (int nt = 0; nt < 4; ++nt) {
                float4 bb = *(const float4*)(bq + 16 * nt + 4 * g);
                const float bs = 0.125f * LOG2E;
                float q0 = acc[M][nt][0] + bb.x * bs;
                float q1 = acc[M][nt][1] + bb.y * bs;
                float q2 = acc[M][nt][2] + bb.z * bs;
                float q3 = acc[M][nt][3] + bb.w * bs;
                int ks = nt >> 1, h = nt & 1;
                size_t qoff = ((size_t)(rg * 2 + ks) * 64 + lane) * 8 + h * 4;
                *(uint2*)(qfrag + qoff) = make_uint2(pk2(q0, q1), pk2(q2, q3));
            }
        } else if (w == 1) {
#pragma unroll
            for (int nt = 0; nt < 4; ++nt) {
                float4 bb = *(const float4*)(bk + 16 * nt + 4 * g);
                float k0 = acc[M][nt][0] + bb.x;
                float k1 = acc[M][nt][1] + bb.y;
                float k2 = acc[M][nt][2] + bb.z;
                float k3 = acc[M][nt][3] + bb.w;
                int ks = nt >> 1, h = nt & 1;
                size_t kfi = ((size_t)((b * 64 + tc) * 4 + c) * 2 + ks);
                size_t koff = (kfi * 64 + lane) * 8 + h * 4;
                *(uint2*)(kfrag + koff) = make_uint2(pk2(k0, k1), pk2(k2, k3));
            }
        } else {
            const int vks = c >> 1, vh = c & 1;
#pragma unroll
            for (int nt = 0; nt < 4; ++nt) {
                float bvv = bv[16 * nt + l15];
                float v0 = acc[M][nt][0] + bvv;
                float v1 = acc[M][nt][1] + bvv;
                float v2 = acc[M][nt][2] + bvv;
                float v3 = acc[M][nt][3] + bvv;
                size_t vfi = ((size_t)((b * 64 + tc) * 4 + nt) * 2 + vks);
                size_t voff = (vfi * 64 + lane) * 8 + vh * 4;
                *(uint2*)(vfrag + voff) = make_uint2(pk2(v0, v1), pk2(v2, v3));
            }
        }
    }
}

// ---------------------------------------------------------------------------
// Flash attention (best-measured): 4 waves x 64 q-rows (M=4), KV-split S,
// grid 64*S, fully unrolled chunk loop (compile-time CPS). K reg-double-
// buffered, V at body top, sched_barrier-pinned burst issue. setprio
// around MFMA. Static-max log2 softmax. l via MFMA-with-ones.
// ---------------------------------------------------------------------------
#define LOADK(KD, CH) do { \
    const uint4* p_ = kb0 + (size_t)(CH) * 512; \
    _Pragma("unroll") \
    for (int c_ = 0; c_ < 4; ++c_) { \
        KD[c_][0].q4 = p_[(c_ * 2 + 0) * 64]; \
        KD[c_][1].q4 = p_[(c_ * 2 + 1) * 64]; \
    } } while (0)

#define LOADV(VD, CH) do { \
    const uint4* p_ = vb0 + (size_t)(CH) * 512; \
    _Pragma("unroll") \
    for (int c_ = 0; c_ < 4; ++c_) { \
        VD[c_][0].q4 = p_[(c_ * 2 + 0) * 64]; \
        VD[c_][1].q4 = p_[(c_ * 2 + 1) * 64]; \
    } } while (0)

#define BODY(KC, KN, CH, CHN) do { \
    Frag vC[4][2]; \
    LOADV(vC, CH); \
    LOADK(KN, CHN); \
    __builtin_amdgcn_sched_barrier(0); \
    _Pragma("unroll") \
    for (int M_ = 0; M_ < 4; ++M_) { \
        f32x4 sD[4]; \
        __builtin_amdgcn_s_setprio(1); \
        _Pragma("unroll") \
        for (int c_ = 0; c_ < 4; ++c_) { \
            f32x4 D = (f32x4){0.f,0.f,0.f,0.f}; \
            D = MFMA16(KC[c_][0].s, qf[M_][0].s, D); \
            D = MFMA16(KC[c_][1].s, qf[M_][1].s, D); \
            sD[c_] = D; \
        } \
        __builtin_amdgcn_s_setprio(0); \
        Frag pa0, pa1; \
        _Pragma("unroll") \
        for (int c_ = 0; c_ < 4; ++c_) { \
            float p0 = __builtin_exp2f(sD[c_][0]); \
            float p1 = __builtin_exp2f(sD[c_][1]); \
            float p2 = __builtin_exp2f(sD[c_][2]); \
            float p3 = __builtin_exp2f(sD[c_][3]); \
            uint2 pk_ = make_uint2(pk2(p0, p1), pk2(p2, p3)); \
            if (c_ < 2) pa0.d2[c_ & 1] = pk_; else pa1.d2[c_ & 1] = pk_; \
        } \
        __builtin_amdgcn_s_setprio(1); \
        lacc[M_] = MFMA16(pa0.s, ones_.s, lacc[M_]); \
        lacc[M_] = MFMA16(pa1.s, ones_.s, lacc[M_]); \
        _Pragma("unroll") \
        for (int dc_ = 0; dc_ < 4; ++dc_) { \
            acc[M_][dc_] = MFMA16(pa0.s, vC[dc_][0].s, acc[M_][dc_]); \
            acc[M_][dc_] = MFMA16(pa1.s, vC[dc_][1].s, acc[M_][dc_]); \
        } \
        __builtin_amdgcn_s_setprio(0); \
    } } while (0)

template<int CPST>
__global__ __launch_bounds__(256, 2) void attn_kernel(
    const unsigned short* __restrict__ qfrag,
    const unsigned short* __restrict__ kfrag,
    const unsigned short* __restrict__ vfrag,
    uint2* __restrict__ OpartU, float* __restrict__ lml,
    int SBITS)
{
    const int tid = threadIdx.x;
    const int lane = tid & 63;
    const int w = tid >> 6;
    const int l15 = lane & 15, g = lane >> 4;
    const int split  = blockIdx.x & ((1 << SBITS) - 1);   // XCD-pinned
    const int qblock = blockIdx.x >> SBITS;
    const int gw = qblock * 4 + w;             // 64-row group 0..255
    const int b = gw >> 6;                     // batch
    const int tcg0 = b * 64 + split * CPST;

    const uint4* qf4 = (const uint4*)qfrag;
    const uint4* kb0 = (const uint4*)kfrag + (size_t)tcg0 * 512 + lane;
    const uint4* vb0 = (const uint4*)vfrag + (size_t)tcg0 * 512 + lane;

    Frag qf[4][2];
#pragma unroll
    for (int M = 0; M < 4; ++M)
#pragma unroll
        for (int ks = 0; ks < 2; ++ks)
            qf[M][ks].q4 = qf4[((size_t)((gw * 4 + M) * 2 + ks)) * 64 + lane];

    Frag ones_;
    ones_.d2[0] = make_uint2(0x3F803F80u, 0x3F803F80u);
    ones_.d2[1] = make_uint2(0x3F803F80u, 0x3F803F80u);

    f32x4 acc[4][4], lacc[4];
#pragma unroll
    for (int M = 0; M < 4; ++M) {
        lacc[M] = (f32x4){0.f,0.f,0.f,0.f};
#pragma unroll
        for (int dc = 0; dc < 4; ++dc) acc[M][dc] = (f32x4){0.f,0.f,0.f,0.f};
    }

    Frag kA[4][2], kB[4][2];
    LOADK(kA, 0);

#pragma unroll
    for (int ch = 0; ch < CPST; ch += 2) {
        const int c1 = (ch + 1 < CPST) ? (ch + 1) : ch;
        const int c2 = (ch + 2 < CPST) ? (ch + 2) : ch;
        BODY(kA, kB, ch, c1);
        BODY(kB, kA, c1, c2);
    }

    // epilogue: bf16 partials; lacc[M][r] = l for q-row 16M+4g+r
#pragma unroll
    for (int M = 0; M < 4; ++M) {
#pragma unroll
        for (int dc = 0; dc < 4; ++dc)
            OpartU[((size_t)(split * 256 + gw) * 16 + M * 4 + dc) * 64 + lane] =
                make_uint2(pk2(acc[M][dc][0], acc[M][dc][1]),
                           pk2(acc[M][dc][2], acc[M][dc][3]));
        if (l15 == 0)
            *(f32x4*)(lml + (size_t)(split * 256 + gw) * 64 + M * 16 + 4 * g) = lacc[M];
    }
}

// ---------------------------------------------------------------------------
// Merge S partials (shared static max -> plain weighted sums, no exp).
// ---------------------------------------------------------------------------
__global__ __launch_bounds__(256) void merge_kernel(
    const uint2* __restrict__ OpartU, const float* __restrict__ lml,
    float* __restrict__ out, int S)
{
    int gid = blockIdx.x * 256 + threadIdx.x;   // 0..262143
    int lane = gid & 63;
    int dc = (gid >> 6) & 3;
    int M  = (gid >> 8) & 3;
    int gw = gid >> 10;                         // 0..255
    int l15 = lane & 15, g = lane >> 4;

    float o0 = 0.f, o1 = 0.f, o2 = 0.f, o3 = 0.f;
    float L0 = 0.f, L1 = 0.f, L2 = 0.f, L3 = 0.f;
    for (int s = 0; s < S; ++s) {
        uint2 pv = OpartU[((size_t)(s * 256 + gw) * 16 + M * 4 + dc) * 64 + lane];
        float4 lv = *(const float4*)(lml + (size_t)(s * 256 + gw) * 64 + M * 16 + 4 * g);
        o0 += __uint_as_float(pv.x << 16);
        o1 += __uint_as_float(pv.x & 0xFFFF0000u);
        o2 += __uint_as_float(pv.y << 16);
        o3 += __uint_as_float(pv.y & 0xFFFF0000u);
        L0 += lv.x; L1 += lv.y; L2 += lv.z; L3 += lv.w;
    }
    size_t row = (size_t)gw * 64 + M * 16 + 4 * g;
    int col = 16 * dc + l15;
    out[(row + 0) * 64 + col] = o0 / L0;
    out[(row + 1) * 64 + col] = o1 / L1;
    out[(row + 2) * 64 + col] = o2 / L2;
    out[(row + 3) * 64 + col] = o3 / L3;
}

extern "C" void kernel_launch(void* const* d_in, const int* in_sizes, int n_in,
                              void* d_out, int out_size, void* d_ws, size_t ws_size,
                              hipStream_t stream) {
    (void)in_sizes; (void)n_in; (void)out_size;
    const float* x  = (const float*)d_in[0];
    const float* Wq = (const float*)d_in[1];
    const float* bq = (const float*)d_in[2];
    const float* Wk = (const float*)d_in[3];
    const float* bk = (const float*)d_in[4];
    const float* Wv = (const float*)d_in[5];
    const float* bv = (const float*)d_in[6];
    float* out = (float*)d_out;

    char* ws = (char*)d_ws;
    unsigned short* qfrag = (unsigned short*)(ws + OFF_Q);
    unsigned short* kfrag = (unsigned short*)(ws + OFF_K);
    unsigned short* vfrag = (unsigned short*)(ws + OFF_V);
    unsigned short* wfrag = (unsigned short*)(ws + OFF_W);

    const size_t oneO = (size_t)256 * 16 * 64 * 8;  // 2 MB per split (bf16)
    const size_t oneL = (size_t)256 * 64 * 4;       // 64 KB per split
    int S = 8, SBITS = 3;
    if (ws_size < (size_t)OFF_O + 8 * (oneO + oneL)) { S = 4; SBITS = 2; }
    if (ws_size < (size_t)OFF_O + 4 * (oneO + oneL)) { S = 2; SBITS = 1; }
    uint2* OpartU = (uint2*)(ws + OFF_O);
    float* lml    = (float*)(ws + OFF_O + (size_t)S * oneO);

    hipLaunchKernelGGL(wprep_kernel, dim3(48), dim3(256), 0, stream,
                       Wq, Wk, Wv, wfrag);
    hipLaunchKernelGGL(qkv_kernel, dim3(512), dim3(192), 0, stream,
                       x, bq, bk, bv, wfrag, qfrag, kfrag, vfrag);
    if (S == 8)
        hipLaunchKernelGGL(attn_kernel<8>,  dim3(64 * 8), dim3(256), 0, stream,
                           qfrag, kfrag, vfrag, OpartU, lml, 3);
    else if (S == 4)
        hipLaunchKernelGGL(attn_kernel<16>, dim3(64 * 4), dim3(256), 0, stream,
                           qfrag, kfrag, vfrag, OpartU, lml, 2);
    else
        hipLaunchKernelGGL(attn_kernel<32>, dim3(64 * 2), dim3(256), 0, stream,
                           qfrag, kfrag, vfrag, OpartU, lml, 1);
    hipLaunchKernelGGL(merge_kernel, dim3(1024), dim3(256), 0, stream,
                       OpartU, lml, out, S);
}